// Round 4
// baseline (2533.804 us; speedup 1.0000x reference)
//
#include <hip/hip_runtime.h>
#include <math.h>

// ---------------------------------------------------------------------------
// GCN layer: out = tanh( scatter_add(adj_vals * h[src] -> dst)
//                        + seq @ w_proj + b_proj + bias ),   h = seq @ w_fc
// N=100000, E=1600000, D=128, fp32.
// R3 -> R4:
//  * scatter: 782 bucket cursors (dst>>7) instead of 100K node cursors ->
//    consecutive winners write adjacent slots (same 64B line); XCD-filtered
//    (blockIdx&7 == bucket&7, round-robin dispatch heuristic) so each line is
//    written by ONE XCD's L2 and merges. R3 showed 64B writeback per 8B store.
//  * aggregate: per-bucket block, 128x128 fp32 accumulator in 64KB LDS,
//    LDS float atomics; kills per-node degree imbalance + fine CSR build.
//  * mm: W converted to bf16 hi/lo ONCE (wconv) instead of per-block.
// ---------------------------------------------------------------------------

typedef __attribute__((ext_vector_type(8))) short short8;
typedef __attribute__((ext_vector_type(4))) float float4v;

static __device__ __forceinline__ short f2bf(float x) {
    unsigned u = __float_as_uint(x);
    unsigned r = (u + 0x7fffu + ((u >> 16) & 1u)) >> 16;   // RNE
    return (short)r;
}
static __device__ __forceinline__ float bf2f(short h) {
    return __uint_as_float(((unsigned)(unsigned short)h) << 16);
}

// ---------------- W pre-conversion: w[k][c] fp32 -> whi/wlo[c][k] bf16 ------
__global__ __launch_bounds__(256)
void wconv_kernel(const float* __restrict__ w, short* __restrict__ whi,
                  short* __restrict__ wlo) {
    const int i = blockIdx.x * 256 + threadIdx.x;   // 4096 float4s
    const float4 v = ((const float4*)w)[i];
    const int k = i >> 5;
    const int c4 = (i & 31) * 4;
    float xs[4] = {v.x, v.y, v.z, v.w};
    #pragma unroll
    for (int j = 0; j < 4; j++) {
        const short hi = f2bf(xs[j]);
        const short lo = f2bf(xs[j] - bf2f(hi));
        whi[(c4 + j) * 128 + k] = hi;
        wlo[(c4 + j) * 128 + k] = lo;
    }
}

// ---------------- MFMA matmul: out[N x 128] = seq[N x 128] @ w[128 x 128] ---
// A*B ~= Ah*Bh + Ah*Bl + Al*Bh (split bf16, rel err ~1e-5).
// Block: 256 thr = 4 waves; 64 rows/block; W (pre-converted) staged in LDS.
#define KP 136

__global__ __launch_bounds__(256, 2)
void mm_mfma_kernel(const float* __restrict__ seq, const short* __restrict__ whi,
                    const short* __restrict__ wlo,
                    const float* __restrict__ b0p, const float* __restrict__ b1p,
                    float* __restrict__ out, int N, int add_bias) {
    __shared__ short wt_hi[128 * KP];
    __shared__ short wt_lo[128 * KP];

    const int tid = threadIdx.x;
    // copy pre-converted W ([c][k], 16 float4 per row) into padded LDS rows
    for (int i = tid; i < 2048; i += 256) {
        const int row = i >> 4;
        const int k8  = (i & 15) * 8;           // short offset within row
        *(float4*)&wt_hi[row * KP + k8] = ((const float4*)whi)[i];
        *(float4*)&wt_lo[row * KP + k8] = ((const float4*)wlo)[i];
    }
    __syncthreads();

    const int wave = tid >> 6;
    const int lane = tid & 63;
    const int q = lane >> 4;        // quad 0..3
    const int c = lane & 15;        // 0..15
    const int R = blockIdx.x * 64 + wave * 16;
    const int rowL = (R + c < N) ? (R + c) : (N - 1);

    float4v acc[8];
    #pragma unroll
    for (int ct = 0; ct < 8; ct++) acc[ct] = (float4v){0.f, 0.f, 0.f, 0.f};

    #pragma unroll
    for (int t = 0; t < 4; t++) {              // k-steps of 32
        const int kk = t * 32 + q * 8;
        const float4 a0 = *(const float4*)&seq[(size_t)rowL * 128 + kk];
        const float4 a1 = *(const float4*)&seq[(size_t)rowL * 128 + kk + 4];
        float xs[8] = {a0.x, a0.y, a0.z, a0.w, a1.x, a1.y, a1.z, a1.w};
        union { short s[8]; short8 v; } ahi, alo;
        #pragma unroll
        for (int j = 0; j < 8; j++) {
            const short hi = f2bf(xs[j]);
            ahi.s[j] = hi;
            alo.s[j] = f2bf(xs[j] - bf2f(hi));
        }
        #pragma unroll
        for (int ct = 0; ct < 8; ct++) {
            const int n = ct * 16 + c;
            const short8 bhi = *(const short8*)&wt_hi[n * KP + kk];
            const short8 blo = *(const short8*)&wt_lo[n * KP + kk];
            acc[ct] = __builtin_amdgcn_mfma_f32_16x16x32_bf16(ahi.v, bhi, acc[ct], 0, 0, 0);
            acc[ct] = __builtin_amdgcn_mfma_f32_16x16x32_bf16(ahi.v, blo, acc[ct], 0, 0, 0);
            acc[ct] = __builtin_amdgcn_mfma_f32_16x16x32_bf16(alo.v, bhi, acc[ct], 0, 0, 0);
        }
    }

    // epilogue: C/D layout col = lane&15, row = quad*4 + reg
    #pragma unroll
    for (int ct = 0; ct < 8; ct++) {
        const int col = ct * 16 + c;
        float badd = 0.f;
        if (add_bias) badd = b0p[col] + b1p[col];
        #pragma unroll
        for (int r = 0; r < 4; r++) {
            const int row = R + q * 4 + r;
            if (row < N) out[(size_t)row * 128 + col] = acc[ct][r] + badd;
        }
    }
}

// ---------------- bucket build (bucket = dst >> 7, 128 nodes each) ---------

__global__ __launch_bounds__(256)
void hist_kernel(const int* __restrict__ edst, int* __restrict__ bcnt, int E) {
    const int stride = gridDim.x * blockDim.x;
    for (int e = blockIdx.x * blockDim.x + threadIdx.x; e < E; e += stride)
        atomicAdd(&bcnt[edst[e] >> 7], 1);
}

// Single block: exclusive scan of 8-aligned bucket counts (NB <= 1024).
__global__ __launch_bounds__(256)
void bscan_kernel(const int* __restrict__ bcnt, int* __restrict__ bstart,
                  int* __restrict__ cursor, int NB) {
    __shared__ int s[256];
    const int t = threadIdx.x;
    int pc[4];
    int sum = 0;
    #pragma unroll
    for (int j = 0; j < 4; j++) {
        const int idx = t * 4 + j;
        const int cv = (idx < NB) ? bcnt[idx] : 0;
        pc[j] = (cv + 7) & ~7;                 // 64B-align each bucket start
        sum += pc[j];
    }
    s[t] = sum;
    __syncthreads();
    for (int o = 1; o < 256; o <<= 1) {
        int add = (t >= o) ? s[t - o] : 0;
        __syncthreads();
        s[t] += add;
        __syncthreads();
    }
    int run = s[t] - sum;
    #pragma unroll
    for (int j = 0; j < 4; j++) {
        const int idx = t * 4 + j;
        if (idx < NB) { bstart[idx] = run; cursor[idx] = run; }
        run += pc[j];
    }
}

// XCD-filtered bucket scatter. entry = (src<<7 | dst&127, val) : 8B.
__global__ __launch_bounds__(256)
void scatter_bucket(const int* __restrict__ esrc, const int* __restrict__ edst,
                    const float* __restrict__ vals, int* __restrict__ cursor,
                    int2* __restrict__ sedge, int E) {
    const int xcd = blockIdx.x & 7;
    const int slice = blockIdx.x >> 3;
    const int stride = (gridDim.x >> 3) * 256;
    for (int e = slice * 256 + threadIdx.x; e < E; e += stride) {
        const int d = edst[e];
        const int b = d >> 7;
        if ((b & 7) != xcd) continue;
        const int p = atomicAdd(&cursor[b], 1);
        sedge[p] = make_int2((esrc[e] << 7) | (d & 127), __float_as_int(vals[e]));
    }
}

// One block per bucket: 128x128 fp32 accumulator in LDS (64KB), LDS float
// atomics; lane covers cols l and l+64 (2-way bank access = free).
// Fused tanh(acc + base) epilogue.
__global__ __launch_bounds__(512, 4)
void aggregate_bucket(const int* __restrict__ bstart, const int* __restrict__ bcnt,
                      const int2* __restrict__ sedge, const float* __restrict__ h,
                      float* __restrict__ out, int N) {
    __shared__ float acc[128 * 128];
    const int b = blockIdx.x;
    const int tid = threadIdx.x;

    const float4 z = make_float4(0.f, 0.f, 0.f, 0.f);
    for (int i = tid; i < 4096; i += 512) ((float4*)acc)[i] = z;
    __syncthreads();

    const int beg = bstart[b];
    const int cnt = bcnt[b];
    const int wave = tid >> 6;
    const int lane = tid & 63;

    for (int base = wave * 64; base < cnt; base += 512) {
        const int rem = cnt - base;
        const int g = rem < 64 ? rem : 64;
        int pk = 0;
        float ev = 0.f;
        if (lane < g) {
            const int2 p = sedge[beg + base + lane];
            pk = p.x;
            ev = __int_as_float(p.y);
        }
        int j = 0;
        for (; j + 4 <= g; j += 4) {
            const int   pk0 = __shfl(pk, j),     pk1 = __shfl(pk, j + 1);
            const int   pk2 = __shfl(pk, j + 2), pk3 = __shfl(pk, j + 3);
            const float v0 = __shfl(ev, j),      v1 = __shfl(ev, j + 1);
            const float v2 = __shfl(ev, j + 2),  v3 = __shfl(ev, j + 3);
            const float* r0 = &h[(size_t)(pk0 >> 7) * 128];
            const float* r1 = &h[(size_t)(pk1 >> 7) * 128];
            const float* r2 = &h[(size_t)(pk2 >> 7) * 128];
            const float* r3 = &h[(size_t)(pk3 >> 7) * 128];
            const float a0 = r0[lane], b0 = r0[64 + lane];
            const float a1 = r1[lane], b1 = r1[64 + lane];
            const float a2 = r2[lane], b2 = r2[64 + lane];
            const float a3 = r3[lane], b3 = r3[64 + lane];
            const int d0 = (pk0 & 127) * 128, d1 = (pk1 & 127) * 128;
            const int d2 = (pk2 & 127) * 128, d3 = (pk3 & 127) * 128;
            atomicAdd(&acc[d0 + lane],      v0 * a0);
            atomicAdd(&acc[d0 + 64 + lane], v0 * b0);
            atomicAdd(&acc[d1 + lane],      v1 * a1);
            atomicAdd(&acc[d1 + 64 + lane], v1 * b1);
            atomicAdd(&acc[d2 + lane],      v2 * a2);
            atomicAdd(&acc[d2 + 64 + lane], v2 * b2);
            atomicAdd(&acc[d3 + lane],      v3 * a3);
            atomicAdd(&acc[d3 + 64 + lane], v3 * b3);
        }
        for (; j < g; j++) {
            const int   pkj = __shfl(pk, j);
            const float vj  = __shfl(ev, j);
            const float* rr = &h[(size_t)(pkj >> 7) * 128];
            const int dj = (pkj & 127) * 128;
            atomicAdd(&acc[dj + lane],      vj * rr[lane]);
            atomicAdd(&acc[dj + 64 + lane], vj * rr[64 + lane]);
        }
    }
    __syncthreads();

    for (int i = tid; i < 4096; i += 512) {
        const int r = i >> 5;
        const int node = b * 128 + r;
        if (node < N) {
            const int c4 = (i & 31) * 4;
            const float4 av = ((const float4*)acc)[i];
            float4 bv = *(const float4*)&out[(size_t)node * 128 + c4];
            float4 o;
            o.x = tanhf(av.x + bv.x);
            o.y = tanhf(av.y + bv.y);
            o.z = tanhf(av.z + bv.z);
            o.w = tanhf(av.w + bv.w);
            *(float4*)&out[(size_t)node * 128 + c4] = o;
        }
    }
}

// ---------------- fallback (atomic) path --------------------------------

__global__ __launch_bounds__(256)
void edge_scatter(const int* __restrict__ esrc, const int* __restrict__ edst,
                  const float* __restrict__ vals, const float* __restrict__ h,
                  float* __restrict__ out, int E) {
    const int gtid = blockIdx.x * blockDim.x + threadIdx.x;
    const int wave = gtid >> 6;
    const int lane = threadIdx.x & 63;
    const int nw = (gridDim.x * blockDim.x) >> 6;
    for (int e = wave; e < E; e += nw) {
        const int s = esrc[e];
        const int d = edst[e];
        const float v = vals[e];
        float2 hv = *(const float2*)(h + (size_t)s * 128 + lane * 2);
        float* op = out + (size_t)d * 128 + lane * 2;
        atomicAdd(op, v * hv.x);
        atomicAdd(op + 1, v * hv.y);
    }
}

__global__ __launch_bounds__(256)
void tanh_kernel(float* __restrict__ out, int n4) {
    const int i = blockIdx.x * blockDim.x + threadIdx.x;
    if (i < n4) {
        float4 v = ((float4*)out)[i];
        v.x = tanhf(v.x);
        v.y = tanhf(v.y);
        v.z = tanhf(v.z);
        v.w = tanhf(v.w);
        ((float4*)out)[i] = v;
    }
}

static inline size_t align64(size_t x) { return (x + 63) & ~(size_t)63; }

extern "C" void kernel_launch(void* const* d_in, const int* in_sizes, int n_in,
                              void* d_out, int out_size, void* d_ws, size_t ws_size,
                              hipStream_t stream) {
    const float* seq    = (const float*)d_in[0];
    const int*   esrc   = (const int*)  d_in[1];
    const int*   edst   = (const int*)  d_in[2];
    const float* vals   = (const float*)d_in[3];
    const float* w_fc   = (const float*)d_in[4];
    const float* w_proj = (const float*)d_in[5];
    const float* b_proj = (const float*)d_in[6];
    const float* bias   = (const float*)d_in[7];
    float* out = (float*)d_out;

    const int N = in_sizes[0] / 128;
    const int E = in_sizes[1];
    const int NB = (N + 127) >> 7;

    // workspace layout
    char* ws = (char*)d_ws;
    const size_t o_h     = 0;                                      // N*128 f32
    const size_t o_whif  = align64(o_h    + (size_t)N * 128 * 4);  // 128*128 bf16
    const size_t o_wlof  = align64(o_whif + 32768);
    const size_t o_whip  = align64(o_wlof + 32768);
    const size_t o_wlop  = align64(o_whip + 32768);
    const size_t o_bcnt  = align64(o_wlop + 32768);                // NB i32
    const size_t o_bst   = align64(o_bcnt + (size_t)NB * 4);       // NB i32
    const size_t o_cur   = align64(o_bst  + (size_t)NB * 4);       // NB i32
    const size_t o_sed   = align64(o_cur  + (size_t)NB * 4);       // E+8NB int2
    const size_t need    = o_sed + ((size_t)E + 8 * (size_t)NB) * 8;

    float* h      = (float*)(ws + o_h);
    short* whi_fc = (short*)(ws + o_whif);
    short* wlo_fc = (short*)(ws + o_wlof);
    short* whi_pj = (short*)(ws + o_whip);
    short* wlo_pj = (short*)(ws + o_wlop);
    int*   bcnt   = (int*)  (ws + o_bcnt);
    int*   bstart = (int*)  (ws + o_bst);
    int*   cursor = (int*)  (ws + o_cur);
    int2*  sedge  = (int2*) (ws + o_sed);

    const int mm_blocks = (N + 63) / 64;

    // W conversion (once), then the two matmuls.
    wconv_kernel<<<16, 256, 0, stream>>>(w_fc,   whi_fc, wlo_fc);
    wconv_kernel<<<16, 256, 0, stream>>>(w_proj, whi_pj, wlo_pj);
    mm_mfma_kernel<<<mm_blocks, 256, 0, stream>>>(seq, whi_fc, wlo_fc, nullptr, nullptr, h, N, 0);
    mm_mfma_kernel<<<mm_blocks, 256, 0, stream>>>(seq, whi_pj, wlo_pj, b_proj, bias, out, N, 1);

    if (ws_size >= need && NB <= 1024) {
        hipMemsetAsync(bcnt, 0, (size_t)NB * 4, stream);
        hist_kernel<<<1024, 256, 0, stream>>>(edst, bcnt, E);
        bscan_kernel<<<1, 256, 0, stream>>>(bcnt, bstart, cursor, NB);
        scatter_bucket<<<2048, 256, 0, stream>>>(esrc, edst, vals, cursor, sedge, E);
        aggregate_bucket<<<NB, 512, 0, stream>>>(bstart, bcnt, sedge, h, out, N);
    } else {
        edge_scatter<<<8192, 256, 0, stream>>>(esrc, edst, vals, h, out, E);
        const int n4 = (N * 128) / 4;
        tanh_kernel<<<(n4 + 255) / 256, 256, 0, stream>>>(out, n4);
    }
}

// Round 5
// 993.762 us; speedup vs baseline: 2.5497x; 2.5497x over previous
//
#include <hip/hip_runtime.h>
#include <math.h>

// ---------------------------------------------------------------------------
// GCN layer: out = tanh( scatter_add(adj_vals * h[src] -> dst)
//                        + seq @ w_proj + b_proj + bias ),   h = seq @ w_fc
// N=100000, E=1600000, D=128, fp32.
// R4 -> R5:
//  * aggregate: R4's LDS-float-atomic bucket kernel (1402us, 330GB/s,
//    latency-bound) -> per-bucket LDS counting sort + R3-style register
//    accumulation (R2/R3 achieved 3.6TB/s HBM with that pattern).
//  * buckets of 64 nodes (NB=1563): scatter has few cursors (adjacent slot
//    wins = same 64B line), XCD-filtered so one XCD owns each line; cursor
//    array permuted so each XCD's cursors are on private lines.
//  * mm / wconv unchanged from R4.
// ---------------------------------------------------------------------------

typedef __attribute__((ext_vector_type(8))) short short8;
typedef __attribute__((ext_vector_type(4))) float float4v;

static __device__ __forceinline__ short f2bf(float x) {
    unsigned u = __float_as_uint(x);
    unsigned r = (u + 0x7fffu + ((u >> 16) & 1u)) >> 16;   // RNE
    return (short)r;
}
static __device__ __forceinline__ float bf2f(short h) {
    return __uint_as_float(((unsigned)(unsigned short)h) << 16);
}

// ---------------- W pre-conversion: w[k][c] fp32 -> whi/wlo[c][k] bf16 ------
__global__ __launch_bounds__(256)
void wconv_kernel(const float* __restrict__ w, short* __restrict__ whi,
                  short* __restrict__ wlo) {
    const int i = blockIdx.x * 256 + threadIdx.x;   // 4096 float4s
    const float4 v = ((const float4*)w)[i];
    const int k = i >> 5;
    const int c4 = (i & 31) * 4;
    float xs[4] = {v.x, v.y, v.z, v.w};
    #pragma unroll
    for (int j = 0; j < 4; j++) {
        const short hi = f2bf(xs[j]);
        const short lo = f2bf(xs[j] - bf2f(hi));
        whi[(c4 + j) * 128 + k] = hi;
        wlo[(c4 + j) * 128 + k] = lo;
    }
}

// ---------------- MFMA matmul: out[N x 128] = seq[N x 128] @ w[128 x 128] ---
// A*B ~= Ah*Bh + Ah*Bl + Al*Bh (split bf16, rel err ~1e-5).
#define KP 136

__global__ __launch_bounds__(256, 2)
void mm_mfma_kernel(const float* __restrict__ seq, const short* __restrict__ whi,
                    const short* __restrict__ wlo,
                    const float* __restrict__ b0p, const float* __restrict__ b1p,
                    float* __restrict__ out, int N, int add_bias) {
    __shared__ short wt_hi[128 * KP];
    __shared__ short wt_lo[128 * KP];

    const int tid = threadIdx.x;
    for (int i = tid; i < 2048; i += 256) {
        const int row = i >> 4;
        const int k8  = (i & 15) * 8;
        *(float4*)&wt_hi[row * KP + k8] = ((const float4*)whi)[i];
        *(float4*)&wt_lo[row * KP + k8] = ((const float4*)wlo)[i];
    }
    __syncthreads();

    const int wave = tid >> 6;
    const int lane = tid & 63;
    const int q = lane >> 4;
    const int c = lane & 15;
    const int R = blockIdx.x * 64 + wave * 16;
    const int rowL = (R + c < N) ? (R + c) : (N - 1);

    float4v acc[8];
    #pragma unroll
    for (int ct = 0; ct < 8; ct++) acc[ct] = (float4v){0.f, 0.f, 0.f, 0.f};

    #pragma unroll
    for (int t = 0; t < 4; t++) {
        const int kk = t * 32 + q * 8;
        const float4 a0 = *(const float4*)&seq[(size_t)rowL * 128 + kk];
        const float4 a1 = *(const float4*)&seq[(size_t)rowL * 128 + kk + 4];
        float xs[8] = {a0.x, a0.y, a0.z, a0.w, a1.x, a1.y, a1.z, a1.w};
        union { short s[8]; short8 v; } ahi, alo;
        #pragma unroll
        for (int j = 0; j < 8; j++) {
            const short hi = f2bf(xs[j]);
            ahi.s[j] = hi;
            alo.s[j] = f2bf(xs[j] - bf2f(hi));
        }
        #pragma unroll
        for (int ct = 0; ct < 8; ct++) {
            const int n = ct * 16 + c;
            const short8 bhi = *(const short8*)&wt_hi[n * KP + kk];
            const short8 blo = *(const short8*)&wt_lo[n * KP + kk];
            acc[ct] = __builtin_amdgcn_mfma_f32_16x16x32_bf16(ahi.v, bhi, acc[ct], 0, 0, 0);
            acc[ct] = __builtin_amdgcn_mfma_f32_16x16x32_bf16(ahi.v, blo, acc[ct], 0, 0, 0);
            acc[ct] = __builtin_amdgcn_mfma_f32_16x16x32_bf16(alo.v, bhi, acc[ct], 0, 0, 0);
        }
    }

    #pragma unroll
    for (int ct = 0; ct < 8; ct++) {
        const int col = ct * 16 + c;
        float badd = 0.f;
        if (add_bias) badd = b0p[col] + b1p[col];
        #pragma unroll
        for (int r = 0; r < 4; r++) {
            const int row = R + q * 4 + r;
            if (row < N) out[(size_t)row * 128 + col] = acc[ct][r] + badd;
        }
    }
}

// ---------------- bucket build (bucket = dst >> 6, 64 nodes each) ----------

__global__ __launch_bounds__(256)
void hist_kernel(const int* __restrict__ edst, int* __restrict__ bcnt, int E) {
    const int stride = gridDim.x * blockDim.x;
    for (int e = blockIdx.x * blockDim.x + threadIdx.x; e < E; e += stride)
        atomicAdd(&bcnt[edst[e] >> 6], 1);
}

static __device__ __forceinline__ int cur_perm(int b) {
    return ((b & 7) << 8) | (b >> 3);   // NB<=2048: b>>3 < 256
}

// Single block: exclusive scan of 8-aligned bucket counts (NB <= 2048).
__global__ __launch_bounds__(256)
void bscan_kernel(const int* __restrict__ bcnt, int* __restrict__ bstart,
                  int* __restrict__ cursor, int NB) {
    __shared__ int s[256];
    const int t = threadIdx.x;
    int pc[8];
    int sum = 0;
    #pragma unroll
    for (int j = 0; j < 8; j++) {
        const int idx = t * 8 + j;
        const int cv = (idx < NB) ? bcnt[idx] : 0;
        pc[j] = (cv + 7) & ~7;                 // 64B-align each bucket start
        sum += pc[j];
    }
    s[t] = sum;
    __syncthreads();
    for (int o = 1; o < 256; o <<= 1) {
        int add = (t >= o) ? s[t - o] : 0;
        __syncthreads();
        s[t] += add;
        __syncthreads();
    }
    int run = s[t] - sum;
    #pragma unroll
    for (int j = 0; j < 8; j++) {
        const int idx = t * 8 + j;
        if (idx < NB) { bstart[idx] = run; cursor[cur_perm(idx)] = run; }
        run += pc[j];
    }
}

// XCD-filtered bucket scatter. entry = (src<<6 | dst&63, val) : 8B.
__global__ __launch_bounds__(256)
void scatter_bucket(const int* __restrict__ esrc, const int* __restrict__ edst,
                    const float* __restrict__ vals, int* __restrict__ cursor,
                    int2* __restrict__ sedge, int E) {
    const int xcd = blockIdx.x & 7;
    const int slice = blockIdx.x >> 3;
    const int stride = (gridDim.x >> 3) * 256;
    for (int e = slice * 256 + threadIdx.x; e < E; e += stride) {
        const int d = edst[e];
        const int b = d >> 6;
        if ((b & 7) != xcd) continue;
        const int p = atomicAdd(&cursor[(xcd << 8) | (b >> 3)], 1);
        sedge[p] = make_int2((esrc[e] << 6) | (d & 63), __float_as_int(vals[e]));
    }
}

// One block (256 thr) per 64-node bucket. Counting-sort edges by node into
// LDS (16KB), then each wave aggregates 16 nodes with REGISTER accumulation:
// LDS broadcast of (src,val), coalesced 512B h-row gather, fused tanh.
#define CAP 2048

__global__ __launch_bounds__(256, 4)
void aggregate_sorted(const int* __restrict__ bstart, const int* __restrict__ bcnt,
                      const int2* __restrict__ sedge, const float* __restrict__ h,
                      float* __restrict__ out, int N) {
    __shared__ int2 ebuf[CAP];
    __shared__ int cnt[64], sc[64], off[65], cur[64];
    const int b = blockIdx.x;
    const int tid = threadIdx.x;
    const int beg = bstart[b];
    const int total = bcnt[b];
    const int cl = total < CAP ? total : CAP;     // edges sorted in LDS

    if (tid < 64) cnt[tid] = 0;
    __syncthreads();
    // pass 1: count by node-low6
    for (int i = tid; i < cl; i += 256)
        atomicAdd(&cnt[sedge[beg + i].x & 63], 1);
    __syncthreads();
    // exclusive scan of 64 counters (Hillis-Steele in LDS)
    if (tid < 64) sc[tid] = cnt[tid];
    __syncthreads();
    for (int o = 1; o < 64; o <<= 1) {
        int add = (tid < 64 && tid >= o) ? sc[tid - o] : 0;
        __syncthreads();
        if (tid < 64) sc[tid] += add;
        __syncthreads();
    }
    if (tid < 64) { off[tid] = sc[tid] - cnt[tid]; cur[tid] = sc[tid] - cnt[tid]; }
    if (tid == 63) off[64] = sc[63];
    __syncthreads();
    // pass 2: place sorted
    for (int i = tid; i < cl; i += 256) {
        const int2 e = sedge[beg + i];
        const int p = atomicAdd(&cur[e.x & 63], 1);
        ebuf[p] = e;
    }
    __syncthreads();

    const int wave = tid >> 6;
    const int lane = tid & 63;
    const float2* hp = (const float2*)h;

    for (int n = wave * 16; n < wave * 16 + 16; n++) {
        const int node = b * 64 + n;
        if (node >= N) break;
        float2 acc = make_float2(0.f, 0.f);
        const int e0 = off[n], e1 = off[n + 1];
        int j = e0;
        for (; j + 4 <= e1; j += 4) {
            const int2 ea = ebuf[j], eb = ebuf[j + 1], ec = ebuf[j + 2], ed = ebuf[j + 3];
            const float2 h0 = hp[(size_t)(ea.x >> 6) * 64 + lane];
            const float2 h1 = hp[(size_t)(eb.x >> 6) * 64 + lane];
            const float2 h2 = hp[(size_t)(ec.x >> 6) * 64 + lane];
            const float2 h3 = hp[(size_t)(ed.x >> 6) * 64 + lane];
            const float v0 = __int_as_float(ea.y), v1 = __int_as_float(eb.y);
            const float v2 = __int_as_float(ec.y), v3 = __int_as_float(ed.y);
            acc.x += v0 * h0.x; acc.y += v0 * h0.y;
            acc.x += v1 * h1.x; acc.y += v1 * h1.y;
            acc.x += v2 * h2.x; acc.y += v2 * h2.y;
            acc.x += v3 * h3.x; acc.y += v3 * h3.y;
        }
        for (; j < e1; j++) {
            const int2 e = ebuf[j];
            const float v = __int_as_float(e.y);
            const float2 hv = hp[(size_t)(e.x >> 6) * 64 + lane];
            acc.x += v * hv.x; acc.y += v * hv.y;
        }
        // overflow edges (cl..total) never happen for this input; correct anyway
        for (int t2 = cl; t2 < total; t2++) {
            const int2 e = sedge[beg + t2];
            if ((e.x & 63) == n) {
                const float v = __int_as_float(e.y);
                const float2 hv = hp[(size_t)(e.x >> 6) * 64 + lane];
                acc.x += v * hv.x; acc.y += v * hv.y;
            }
        }
        const float2 basev = ((const float2*)out)[(size_t)node * 64 + lane];
        float2 r;
        r.x = tanhf(acc.x + basev.x);
        r.y = tanhf(acc.y + basev.y);
        ((float2*)out)[(size_t)node * 64 + lane] = r;
    }
}

// ---------------- fallback (atomic) path --------------------------------

__global__ __launch_bounds__(256)
void edge_scatter(const int* __restrict__ esrc, const int* __restrict__ edst,
                  const float* __restrict__ vals, const float* __restrict__ h,
                  float* __restrict__ out, int E) {
    const int gtid = blockIdx.x * blockDim.x + threadIdx.x;
    const int wave = gtid >> 6;
    const int lane = threadIdx.x & 63;
    const int nw = (gridDim.x * blockDim.x) >> 6;
    for (int e = wave; e < E; e += nw) {
        const int s = esrc[e];
        const int d = edst[e];
        const float v = vals[e];
        float2 hv = *(const float2*)(h + (size_t)s * 128 + lane * 2);
        float* op = out + (size_t)d * 128 + lane * 2;
        atomicAdd(op, v * hv.x);
        atomicAdd(op + 1, v * hv.y);
    }
}

__global__ __launch_bounds__(256)
void tanh_kernel(float* __restrict__ out, int n4) {
    const int i = blockIdx.x * blockDim.x + threadIdx.x;
    if (i < n4) {
        float4 v = ((float4*)out)[i];
        v.x = tanhf(v.x);
        v.y = tanhf(v.y);
        v.z = tanhf(v.z);
        v.w = tanhf(v.w);
        ((float4*)out)[i] = v;
    }
}

static inline size_t align64(size_t x) { return (x + 63) & ~(size_t)63; }

extern "C" void kernel_launch(void* const* d_in, const int* in_sizes, int n_in,
                              void* d_out, int out_size, void* d_ws, size_t ws_size,
                              hipStream_t stream) {
    const float* seq    = (const float*)d_in[0];
    const int*   esrc   = (const int*)  d_in[1];
    const int*   edst   = (const int*)  d_in[2];
    const float* vals   = (const float*)d_in[3];
    const float* w_fc   = (const float*)d_in[4];
    const float* w_proj = (const float*)d_in[5];
    const float* b_proj = (const float*)d_in[6];
    const float* bias   = (const float*)d_in[7];
    float* out = (float*)d_out;

    const int N = in_sizes[0] / 128;
    const int E = in_sizes[1];
    const int NB = (N + 63) >> 6;

    // workspace layout
    char* ws = (char*)d_ws;
    const size_t o_h     = 0;                                      // N*128 f32
    const size_t o_whif  = align64(o_h    + (size_t)N * 128 * 4);
    const size_t o_wlof  = align64(o_whif + 32768);
    const size_t o_whip  = align64(o_wlof + 32768);
    const size_t o_wlop  = align64(o_whip + 32768);
    const size_t o_bcnt  = align64(o_wlop + 32768);                // NB i32
    const size_t o_bst   = align64(o_bcnt + (size_t)NB * 4);       // NB i32
    const size_t o_cur   = align64(o_bst  + (size_t)NB * 4);       // 2048 i32
    const size_t o_sed   = align64(o_cur  + 2048 * 4);             // E+8NB int2
    const size_t need    = o_sed + ((size_t)E + 8 * (size_t)NB) * 8;

    float* h      = (float*)(ws + o_h);
    short* whi_fc = (short*)(ws + o_whif);
    short* wlo_fc = (short*)(ws + o_wlof);
    short* whi_pj = (short*)(ws + o_whip);
    short* wlo_pj = (short*)(ws + o_wlop);
    int*   bcnt   = (int*)  (ws + o_bcnt);
    int*   bstart = (int*)  (ws + o_bst);
    int*   cursor = (int*)  (ws + o_cur);
    int2*  sedge  = (int2*) (ws + o_sed);

    const int mm_blocks = (N + 63) / 64;

    wconv_kernel<<<16, 256, 0, stream>>>(w_fc,   whi_fc, wlo_fc);
    wconv_kernel<<<16, 256, 0, stream>>>(w_proj, whi_pj, wlo_pj);
    mm_mfma_kernel<<<mm_blocks, 256, 0, stream>>>(seq, whi_fc, wlo_fc, nullptr, nullptr, h, N, 0);
    mm_mfma_kernel<<<mm_blocks, 256, 0, stream>>>(seq, whi_pj, wlo_pj, b_proj, bias, out, N, 1);

    if (ws_size >= need && NB <= 2048) {
        hipMemsetAsync(bcnt, 0, (size_t)NB * 4, stream);
        hist_kernel<<<1024, 256, 0, stream>>>(edst, bcnt, E);
        bscan_kernel<<<1, 256, 0, stream>>>(bcnt, bstart, cursor, NB);
        scatter_bucket<<<2048, 256, 0, stream>>>(esrc, edst, vals, cursor, sedge, E);
        aggregate_sorted<<<NB, 256, 0, stream>>>(bstart, bcnt, sedge, h, out, N);
    } else {
        edge_scatter<<<8192, 256, 0, stream>>>(esrc, edst, vals, h, out, E);
        const int n4 = (N * 128) / 4;
        tanh_kernel<<<(n4 + 255) / 256, 256, 0, stream>>>(out, n4);
    }
}

// Round 6
// 404.526 us; speedup vs baseline: 6.2636x; 2.4566x over previous
//
#include <hip/hip_runtime.h>
#include <math.h>

// ---------------------------------------------------------------------------
// GCN layer: out = tanh( scatter_add(adj_vals * h[src] -> dst)
//                        + seq @ w_proj + b_proj + bias ),   h = seq @ w_fc
// N=100000, E=1600000, D=128, fp32.
// R5 -> R6:
//  * R5's scatter_bucket (450us): 1563 value-returning global atomics cursors
//    x ~1000 hits each = RMW serialization wall. Replaced with atomic-free
//    radix partition: per-block LDS histogram -> device scan -> LDS-cursor
//    scatter. Also kills hist_kernel's 1.6M global atomics.
//  * aggregate_sorted / mm / wconv unchanged.
// ---------------------------------------------------------------------------

typedef __attribute__((ext_vector_type(8))) short short8;
typedef __attribute__((ext_vector_type(4))) float float4v;

#define PG 128          // partition blocks (slices)
#define NBMAX 2048      // max buckets (64 nodes each)

static __device__ __forceinline__ short f2bf(float x) {
    unsigned u = __float_as_uint(x);
    unsigned r = (u + 0x7fffu + ((u >> 16) & 1u)) >> 16;   // RNE
    return (short)r;
}
static __device__ __forceinline__ float bf2f(short h) {
    return __uint_as_float(((unsigned)(unsigned short)h) << 16);
}

// ---------------- W pre-conversion: w[k][c] fp32 -> whi/wlo[c][k] bf16 ------
__global__ __launch_bounds__(256)
void wconv_kernel(const float* __restrict__ w, short* __restrict__ whi,
                  short* __restrict__ wlo) {
    const int i = blockIdx.x * 256 + threadIdx.x;   // 4096 float4s
    const float4 v = ((const float4*)w)[i];
    const int k = i >> 5;
    const int c4 = (i & 31) * 4;
    float xs[4] = {v.x, v.y, v.z, v.w};
    #pragma unroll
    for (int j = 0; j < 4; j++) {
        const short hi = f2bf(xs[j]);
        const short lo = f2bf(xs[j] - bf2f(hi));
        whi[(c4 + j) * 128 + k] = hi;
        wlo[(c4 + j) * 128 + k] = lo;
    }
}

// ---------------- MFMA matmul: out[N x 128] = seq[N x 128] @ w[128 x 128] ---
// A*B ~= Ah*Bh + Ah*Bl + Al*Bh (split bf16, rel err ~1e-5).
#define KP 136

__global__ __launch_bounds__(256, 2)
void mm_mfma_kernel(const float* __restrict__ seq, const short* __restrict__ whi,
                    const short* __restrict__ wlo,
                    const float* __restrict__ b0p, const float* __restrict__ b1p,
                    float* __restrict__ out, int N, int add_bias) {
    __shared__ short wt_hi[128 * KP];
    __shared__ short wt_lo[128 * KP];

    const int tid = threadIdx.x;
    for (int i = tid; i < 2048; i += 256) {
        const int row = i >> 4;
        const int k8  = (i & 15) * 8;
        *(float4*)&wt_hi[row * KP + k8] = ((const float4*)whi)[i];
        *(float4*)&wt_lo[row * KP + k8] = ((const float4*)wlo)[i];
    }
    __syncthreads();

    const int wave = tid >> 6;
    const int lane = tid & 63;
    const int q = lane >> 4;
    const int c = lane & 15;
    const int R = blockIdx.x * 64 + wave * 16;
    const int rowL = (R + c < N) ? (R + c) : (N - 1);

    float4v acc[8];
    #pragma unroll
    for (int ct = 0; ct < 8; ct++) acc[ct] = (float4v){0.f, 0.f, 0.f, 0.f};

    #pragma unroll
    for (int t = 0; t < 4; t++) {
        const int kk = t * 32 + q * 8;
        const float4 a0 = *(const float4*)&seq[(size_t)rowL * 128 + kk];
        const float4 a1 = *(const float4*)&seq[(size_t)rowL * 128 + kk + 4];
        float xs[8] = {a0.x, a0.y, a0.z, a0.w, a1.x, a1.y, a1.z, a1.w};
        union { short s[8]; short8 v; } ahi, alo;
        #pragma unroll
        for (int j = 0; j < 8; j++) {
            const short hi = f2bf(xs[j]);
            ahi.s[j] = hi;
            alo.s[j] = f2bf(xs[j] - bf2f(hi));
        }
        #pragma unroll
        for (int ct = 0; ct < 8; ct++) {
            const int n = ct * 16 + c;
            const short8 bhi = *(const short8*)&wt_hi[n * KP + kk];
            const short8 blo = *(const short8*)&wt_lo[n * KP + kk];
            acc[ct] = __builtin_amdgcn_mfma_f32_16x16x32_bf16(ahi.v, bhi, acc[ct], 0, 0, 0);
            acc[ct] = __builtin_amdgcn_mfma_f32_16x16x32_bf16(ahi.v, blo, acc[ct], 0, 0, 0);
            acc[ct] = __builtin_amdgcn_mfma_f32_16x16x32_bf16(alo.v, bhi, acc[ct], 0, 0, 0);
        }
    }

    #pragma unroll
    for (int ct = 0; ct < 8; ct++) {
        const int col = ct * 16 + c;
        float badd = 0.f;
        if (add_bias) badd = b0p[col] + b1p[col];
        #pragma unroll
        for (int r = 0; r < 4; r++) {
            const int row = R + q * 4 + r;
            if (row < N) out[(size_t)row * 128 + col] = acc[ct][r] + badd;
        }
    }
}

// ---------------- atomic-free radix partition (bucket = dst>>6) ------------

// Per-slice LDS histogram -> hcnt[b*PG + g] (bucket-major for the scan).
__global__ __launch_bounds__(256)
void phist_kernel(const int* __restrict__ edst, int* __restrict__ hcnt,
                  int E, int S, int NB) {
    __shared__ int cnt[NBMAX];
    const int g = blockIdx.x;
    const int tid = threadIdx.x;
    for (int b = tid; b < NB; b += 256) cnt[b] = 0;
    __syncthreads();
    const int lo = g * S;
    const int hi = (lo + S < E) ? (lo + S) : E;
    for (int i = lo + tid; i < hi; i += 256)
        atomicAdd(&cnt[edst[i] >> 6], 1);
    __syncthreads();
    for (int b = tid; b < NB; b += 256) hcnt[b * PG + g] = cnt[b];
}

// Exclusive scan over L = NB*PG entries. pscan1: per-block (1024 elems)
// exclusive prefix + block sums.
__global__ __launch_bounds__(256)
void pscan1_kernel(const int* __restrict__ in, int* __restrict__ out,
                   int* __restrict__ bsum, int L) {
    __shared__ int s[256];
    const int t = threadIdx.x;
    const int base = blockIdx.x * 1024 + t * 4;
    int v0 = (base + 0 < L) ? in[base + 0] : 0;
    int v1 = (base + 1 < L) ? in[base + 1] : 0;
    int v2 = (base + 2 < L) ? in[base + 2] : 0;
    int v3 = (base + 3 < L) ? in[base + 3] : 0;
    const int mysum = v0 + v1 + v2 + v3;
    s[t] = mysum;
    __syncthreads();
    for (int o = 1; o < 256; o <<= 1) {
        int add = (t >= o) ? s[t - o] : 0;
        __syncthreads();
        s[t] += add;
        __syncthreads();
    }
    const int excl = s[t] - mysum;
    if (base + 0 < L) out[base + 0] = excl;
    if (base + 1 < L) out[base + 1] = excl + v0;
    if (base + 2 < L) out[base + 2] = excl + v0 + v1;
    if (base + 3 < L) out[base + 3] = excl + v0 + v1 + v2;
    if (t == 255) bsum[blockIdx.x] = s[255];
}

// Single block: exclusive scan of nb (<=256) block sums.
__global__ __launch_bounds__(256)
void pscan2_kernel(const int* __restrict__ bsum, int* __restrict__ ebsum, int nb) {
    __shared__ int s[256];
    const int t = threadIdx.x;
    const int v = (t < nb) ? bsum[t] : 0;
    s[t] = v;
    __syncthreads();
    for (int o = 1; o < 256; o <<= 1) {
        int add = (t >= o) ? s[t - o] : 0;
        __syncthreads();
        s[t] += add;
        __syncthreads();
    }
    if (t < nb) ebsum[t] = s[t] - v;
}

// pos[i] += ebsum[block]; also emit bstart[b] = pos[b*PG] and bstart[NB] = E.
__global__ __launch_bounds__(256)
void paddback_kernel(int* __restrict__ pos, const int* __restrict__ ebsum,
                     int* __restrict__ bstart, int L, int NB, int E) {
    const int add = ebsum[blockIdx.x];
    const int base = blockIdx.x * 1024 + threadIdx.x * 4;
    #pragma unroll
    for (int j = 0; j < 4; j++) {
        const int idx = base + j;
        if (idx < L) {
            const int v = pos[idx] + add;
            pos[idx] = v;
            if ((idx & (PG - 1)) == 0) bstart[idx / PG] = v;
        }
    }
    if (blockIdx.x == 0 && threadIdx.x == 0) bstart[NB] = E;
}

// Atomic-free (global) scatter: LDS cursors seeded from pos.
// entry = (src<<6 | dst&63, val) : 8B.
__global__ __launch_bounds__(256)
void pscatter_kernel(const int* __restrict__ esrc, const int* __restrict__ edst,
                     const float* __restrict__ vals, const int* __restrict__ pos,
                     int2* __restrict__ sedge, int E, int S, int NB) {
    __shared__ int cur[NBMAX];
    const int g = blockIdx.x;
    const int tid = threadIdx.x;
    for (int b = tid; b < NB; b += 256) cur[b] = pos[b * PG + g];
    __syncthreads();
    const int lo = g * S;
    const int hi = (lo + S < E) ? (lo + S) : E;
    for (int i = lo + tid; i < hi; i += 256) {
        const int d = edst[i];
        const int p = atomicAdd(&cur[d >> 6], 1);
        sedge[p] = make_int2((esrc[i] << 6) | (d & 63), __float_as_int(vals[i]));
    }
}

// One block (256 thr) per 64-node bucket. Counting-sort edges by node into
// LDS (16KB), then each wave aggregates 16 nodes with REGISTER accumulation:
// coalesced 512B h-row gathers, fused tanh.
#define CAP 2048

__global__ __launch_bounds__(256, 4)
void aggregate_sorted(const int* __restrict__ bstart, const int2* __restrict__ sedge,
                      const float* __restrict__ h, float* __restrict__ out, int N) {
    __shared__ int2 ebuf[CAP];
    __shared__ int cnt[64], sc[64], off[65], cur[64];
    const int b = blockIdx.x;
    const int tid = threadIdx.x;
    const int beg = bstart[b];
    const int total = bstart[b + 1] - beg;
    const int cl = total < CAP ? total : CAP;     // edges sorted in LDS

    if (tid < 64) cnt[tid] = 0;
    __syncthreads();
    for (int i = tid; i < cl; i += 256)
        atomicAdd(&cnt[sedge[beg + i].x & 63], 1);
    __syncthreads();
    if (tid < 64) sc[tid] = cnt[tid];
    __syncthreads();
    for (int o = 1; o < 64; o <<= 1) {
        int add = (tid < 64 && tid >= o) ? sc[tid - o] : 0;
        __syncthreads();
        if (tid < 64) sc[tid] += add;
        __syncthreads();
    }
    if (tid < 64) { off[tid] = sc[tid] - cnt[tid]; cur[tid] = sc[tid] - cnt[tid]; }
    if (tid == 63) off[64] = sc[63];
    __syncthreads();
    for (int i = tid; i < cl; i += 256) {
        const int2 e = sedge[beg + i];
        const int p = atomicAdd(&cur[e.x & 63], 1);
        ebuf[p] = e;
    }
    __syncthreads();

    const int wave = tid >> 6;
    const int lane = tid & 63;
    const float2* hp = (const float2*)h;

    for (int n = wave * 16; n < wave * 16 + 16; n++) {
        const int node = b * 64 + n;
        if (node >= N) break;
        float2 acc = make_float2(0.f, 0.f);
        const int e0 = off[n], e1 = off[n + 1];
        int j = e0;
        for (; j + 4 <= e1; j += 4) {
            const int2 ea = ebuf[j], eb = ebuf[j + 1], ec = ebuf[j + 2], ed = ebuf[j + 3];
            const float2 h0 = hp[(size_t)(ea.x >> 6) * 64 + lane];
            const float2 h1 = hp[(size_t)(eb.x >> 6) * 64 + lane];
            const float2 h2 = hp[(size_t)(ec.x >> 6) * 64 + lane];
            const float2 h3 = hp[(size_t)(ed.x >> 6) * 64 + lane];
            const float v0 = __int_as_float(ea.y), v1 = __int_as_float(eb.y);
            const float v2 = __int_as_float(ec.y), v3 = __int_as_float(ed.y);
            acc.x += v0 * h0.x; acc.y += v0 * h0.y;
            acc.x += v1 * h1.x; acc.y += v1 * h1.y;
            acc.x += v2 * h2.x; acc.y += v2 * h2.y;
            acc.x += v3 * h3.x; acc.y += v3 * h3.y;
        }
        for (; j < e1; j++) {
            const int2 e = ebuf[j];
            const float v = __int_as_float(e.y);
            const float2 hv = hp[(size_t)(e.x >> 6) * 64 + lane];
            acc.x += v * hv.x; acc.y += v * hv.y;
        }
        for (int t2 = cl; t2 < total; t2++) {     // LDS overflow tail (rare)
            const int2 e = sedge[beg + t2];
            if ((e.x & 63) == n) {
                const float v = __int_as_float(e.y);
                const float2 hv = hp[(size_t)(e.x >> 6) * 64 + lane];
                acc.x += v * hv.x; acc.y += v * hv.y;
            }
        }
        const float2 basev = ((const float2*)out)[(size_t)node * 64 + lane];
        float2 r;
        r.x = tanhf(acc.x + basev.x);
        r.y = tanhf(acc.y + basev.y);
        ((float2*)out)[(size_t)node * 64 + lane] = r;
    }
}

// ---------------- fallback (atomic) path --------------------------------

__global__ __launch_bounds__(256)
void edge_scatter(const int* __restrict__ esrc, const int* __restrict__ edst,
                  const float* __restrict__ vals, const float* __restrict__ h,
                  float* __restrict__ out, int E) {
    const int gtid = blockIdx.x * blockDim.x + threadIdx.x;
    const int wave = gtid >> 6;
    const int lane = threadIdx.x & 63;
    const int nw = (gridDim.x * blockDim.x) >> 6;
    for (int e = wave; e < E; e += nw) {
        const int s = esrc[e];
        const int d = edst[e];
        const float v = vals[e];
        float2 hv = *(const float2*)(h + (size_t)s * 128 + lane * 2);
        float* op = out + (size_t)d * 128 + lane * 2;
        atomicAdd(op, v * hv.x);
        atomicAdd(op + 1, v * hv.y);
    }
}

__global__ __launch_bounds__(256)
void tanh_kernel(float* __restrict__ out, int n4) {
    const int i = blockIdx.x * blockDim.x + threadIdx.x;
    if (i < n4) {
        float4 v = ((float4*)out)[i];
        v.x = tanhf(v.x);
        v.y = tanhf(v.y);
        v.z = tanhf(v.z);
        v.w = tanhf(v.w);
        ((float4*)out)[i] = v;
    }
}

static inline size_t align64(size_t x) { return (x + 63) & ~(size_t)63; }

extern "C" void kernel_launch(void* const* d_in, const int* in_sizes, int n_in,
                              void* d_out, int out_size, void* d_ws, size_t ws_size,
                              hipStream_t stream) {
    const float* seq    = (const float*)d_in[0];
    const int*   esrc   = (const int*)  d_in[1];
    const int*   edst   = (const int*)  d_in[2];
    const float* vals   = (const float*)d_in[3];
    const float* w_fc   = (const float*)d_in[4];
    const float* w_proj = (const float*)d_in[5];
    const float* b_proj = (const float*)d_in[6];
    const float* bias   = (const float*)d_in[7];
    float* out = (float*)d_out;

    const int N = in_sizes[0] / 128;
    const int E = in_sizes[1];
    const int NB = (N + 63) >> 6;
    const int L  = NB * PG;                       // histogram entries
    const int S  = (E + PG - 1) / PG;             // slice size
    const int nsb = (L + 1023) / 1024;            // scan blocks

    // workspace layout
    char* ws = (char*)d_ws;
    const size_t o_h     = 0;                                      // N*128 f32
    const size_t o_whif  = align64(o_h    + (size_t)N * 128 * 4);
    const size_t o_wlof  = align64(o_whif + 32768);
    const size_t o_whip  = align64(o_wlof + 32768);
    const size_t o_wlop  = align64(o_whip + 32768);
    const size_t o_hc    = align64(o_wlop + 32768);                // L i32 (hist)
    const size_t o_pos   = align64(o_hc   + (size_t)L * 4);        // L i32 (scan)
    const size_t o_bs    = align64(o_pos  + (size_t)L * 4);        // NB+1 i32
    const size_t o_bsum  = align64(o_bs   + (size_t)(NB + 1) * 4); // 256 i32
    const size_t o_ebs   = align64(o_bsum + 1024);                 // 256 i32
    const size_t o_sed   = align64(o_ebs  + 1024);                 // E int2
    const size_t need    = o_sed + (size_t)E * 8;

    float* h      = (float*)(ws + o_h);
    short* whi_fc = (short*)(ws + o_whif);
    short* wlo_fc = (short*)(ws + o_wlof);
    short* whi_pj = (short*)(ws + o_whip);
    short* wlo_pj = (short*)(ws + o_wlop);
    int*   hcnt   = (int*)  (ws + o_hc);
    int*   pos    = (int*)  (ws + o_pos);
    int*   bstart = (int*)  (ws + o_bs);
    int*   bsum   = (int*)  (ws + o_bsum);
    int*   ebsum  = (int*)  (ws + o_ebs);
    int2*  sedge  = (int2*) (ws + o_sed);

    const int mm_blocks = (N + 63) / 64;

    wconv_kernel<<<16, 256, 0, stream>>>(w_fc,   whi_fc, wlo_fc);
    wconv_kernel<<<16, 256, 0, stream>>>(w_proj, whi_pj, wlo_pj);
    mm_mfma_kernel<<<mm_blocks, 256, 0, stream>>>(seq, whi_fc, wlo_fc, nullptr, nullptr, h, N, 0);
    mm_mfma_kernel<<<mm_blocks, 256, 0, stream>>>(seq, whi_pj, wlo_pj, b_proj, bias, out, N, 1);

    if (ws_size >= need && NB <= NBMAX && nsb <= 256) {
        phist_kernel<<<PG, 256, 0, stream>>>(edst, hcnt, E, S, NB);
        pscan1_kernel<<<nsb, 256, 0, stream>>>(hcnt, pos, bsum, L);
        pscan2_kernel<<<1, 256, 0, stream>>>(bsum, ebsum, nsb);
        paddback_kernel<<<nsb, 256, 0, stream>>>(pos, ebsum, bstart, L, NB, E);
        pscatter_kernel<<<PG, 256, 0, stream>>>(esrc, edst, vals, pos, sedge, E, S, NB);
        aggregate_sorted<<<NB, 256, 0, stream>>>(bstart, sedge, h, out, N);
    } else {
        edge_scatter<<<8192, 256, 0, stream>>>(esrc, edst, vals, h, out, E);
        const int n4 = (N * 128) / 4;
        tanh_kernel<<<(n4 + 255) / 256, 256, 0, stream>>>(out, n4);
    }
}